// Round 13
// baseline (74.938 us; speedup 1.0000x reference)
//
#include <hip/hip_runtime.h>
#include <hip/hip_bf16.h>
#include <stdint.h>

// SmoothLoss: total = (1/24) * sum over 24 offsets of mean( exp(-||dx||^2/200) * ||dy||_1 )
// x = rgb2ycbcr(input) (bias cancels in diffs), y = output. 12 offsets, weight 2x.
// R12 = R11 champion with ONE structural parameter change: TH=2 (ROWS=4) ->
// LDS 49,920B -> 3 blocks/CU = 24 static waves/CU (+50% TLP) to attack the
// ~43% stall fraction. 2 own rows x 512 cols = 1024 px/block -> 2 px/lane;
// Phase-C windows become float2 (ds_read_b64, 8B lane stride: 2-way bank
// aliasing = free). Total LDS bytes unchanged. Staging halo ratio 1.5->2.0.
// Everything else identical: gload_lds staging, poisoned halos (plane0=1e19 ->
// v_exp flushes to 0, no bounds checks), Phase B in-place ycbcr with
// K2=sqrt(0.005/ln2) baked in, raw __builtin_amdgcn_exp2f, s_setprio around
// compute clusters.

#define B_ 16
#define H_ 512
#define W_ 512
#define HW_ (H_ * W_)
#define CHW_ (3 * HW_)

#define TH 2          // own rows per block
#define ROWS 4        // TH + 2 bottom halo
#define COLS 520      // 4 pad | 512 | 4 pad ; img col j <-> lds col j+4
#define NTHREADS 512
#define POISON 1e19f
#define K2 0.08493218049364766f  // sqrt(0.005 / ln(2))

__global__ void zero_out_kernel(float* p) { p[0] = 0.0f; }

__device__ __forceinline__ void gload16(const float* gsrc, float* ldst) {
  __builtin_amdgcn_global_load_lds(
      (const __attribute__((address_space(1))) void*)gsrc,
      (__attribute__((address_space(3))) void*)ldst, 16, 0, 0);
}

// O[plane][q]: q <-> img col j0+q (4 floats: own 2 px + 2 right)
template <int DW>
__device__ __forceinline__ float contrib0(const float (&O)[6][4]) {
  const float scale = 2.0f / (24.0f * (float)B_ * (float)H_ * (float)(W_ - DW));
  float s = 0.0f;
#pragma unroll
  for (int p = 0; p < 2; ++p) {
    float d0 = O[0][p] - O[0][p + DW];
    float d1 = O[1][p] - O[1][p + DW];
    float d2 = O[2][p] - O[2][p + DW];
    float nq = -(d0 * d0 + d1 * d1 + d2 * d2);
    float wgt = __builtin_amdgcn_exp2f(nq);   // raw v_exp_f32
    float l1 = fabsf(O[3][p] - O[3][p + DW]) + fabsf(O[4][p] - O[4][p + DW]) +
               fabsf(O[5][p] - O[5][p + DW]);
    s += wgt * l1;
  }
  return scale * s;
}

// N[plane][q]: q <-> img col j0-2+q (6 floats)
template <int DH, int DW>
__device__ __forceinline__ float contribN(const float (&O)[6][4],
                                          const float (&N)[6][6]) {
  constexpr int AW = DW < 0 ? -DW : DW;
  const float scale =
      2.0f / (24.0f * (float)B_ * (float)(H_ - DH) * (float)(W_ - AW));
  float s = 0.0f;
#pragma unroll
  for (int p = 0; p < 2; ++p) {
    const int ni = p + 2 + DW;
    float d0 = O[0][p] - N[0][ni];
    float d1 = O[1][p] - N[1][ni];
    float d2 = O[2][p] - N[2][ni];
    float nq = -(d0 * d0 + d1 * d1 + d2 * d2);
    float wgt = __builtin_amdgcn_exp2f(nq);   // raw v_exp_f32
    float l1 = fabsf(O[3][p] - N[3][ni]) + fabsf(O[4][p] - N[4][ni]) +
               fabsf(O[5][p] - N[5][ni]);
    s += wgt * l1;
  }
  return scale * s;
}

__global__ __launch_bounds__(NTHREADS, 6) void smooth_loss_kernel(
    const float* __restrict__ in, const float* __restrict__ outp,
    float* __restrict__ result) {
  __shared__ alignas(16) float lds[6][ROWS][COLS];  // 49,920 B -> 3 blocks/CU
  __shared__ float wsum[8];

  const int tid = threadIdx.x;
  const int wv = tid >> 6;     // 0..7
  const int lane = tid & 63;
  const int by = blockIdx.x;   // 0..255 row tile
  const int b = blockIdx.y;    // 0..15 batch
  const int ibase = by * TH;

  const float* inb = in + (size_t)b * CHW_;
  const float* outb = outp + (size_t)b * CHW_;

  // ---- Phase A: async stage. 48 wave-chunks = 4 rows x 6 planes x 2 halves ----
#pragma unroll
  for (int k = 0; k < 6; ++k) {
    int wc = wv + 8 * k;            // wave-uniform, 0..47
    int r = wc / 12;
    int rem = wc - 12 * r;
    int p = rem >> 1;
    int h = rem & 1;
    if (ibase + r < H_) {
      const float* src =
          (p < 3 ? inb + (size_t)p * HW_ : outb + (size_t)(p - 3) * HW_) +
          (size_t)(ibase + r) * W_ + 256 * h + 4 * lane;
      gload16(src, &lds[p][r][4 + 256 * h]);
    }
  }

  // ---- poison halo columns (all rows, all planes): plane0=POISON, others=0 ----
  if (tid < 192) {                 // 6 planes x 4 rows x 8 cols
    int p = tid / 32;
    int rem = tid - 32 * p;
    int r = rem >> 3;
    int ci = rem & 7;
    int col = ci < 4 ? ci : 512 + ci;
    lds[p][r][col] = (p == 0) ? POISON : 0.0f;
  }
  // ---- poison out-of-range bottom halo rows (only last row tile) ----
  if (ibase + 2 >= H_) {           // rows 2,3 got no gload
    for (int c = tid; c < 6 * 2 * 130; c += NTHREADS) {
      int p = c / 260;
      int rem = c - 260 * p;
      int r = 2 + rem / 130;
      int q4 = rem % 130;
      float v = (p == 0) ? POISON : 0.0f;
      *(float4*)&lds[p][r][4 * q4] = make_float4(v, v, v, v);
    }
  }

  __syncthreads();  // drains gload_lds (vmcnt) + ds_writes

  // ---- Phase B: in-place rgb -> ycbcr, coefficients x K2 ----
  {
#pragma unroll
    for (int k = 0; k < 2; ++k) {
      int c = tid + NTHREADS * k;   // 520 float4-items = 4 rows x 130
      if (c < ROWS * 130) {
        int r = c / 130;
        int q4 = c - 130 * r;
        int col = 4 * q4;
        float4 rr = *(const float4*)&lds[0][r][col];
        float4 gg = *(const float4*)&lds[1][r][col];
        float4 bb = *(const float4*)&lds[2][r][col];
        float rv[4] = {rr.x, rr.y, rr.z, rr.w};
        float gv[4] = {gg.x, gg.y, gg.z, gg.w};
        float bv[4] = {bb.x, bb.y, bb.z, bb.w};
        float x0[4], x1[4], x2[4];
#pragma unroll
        for (int m = 0; m < 4; ++m) {
          x0[m] = (0.257f * K2) * rv[m] + (0.564f * K2) * gv[m] + (0.098f * K2) * bv[m];
          x1[m] = (-0.148f * K2) * rv[m] + (-0.291f * K2) * gv[m] + (0.439f * K2) * bv[m];
          x2[m] = (0.439f * K2) * rv[m] + (-0.368f * K2) * gv[m] + (-0.071f * K2) * bv[m];
        }
        *(float4*)&lds[0][r][col] = make_float4(x0[0], x0[1], x0[2], x0[3]);
        *(float4*)&lds[1][r][col] = make_float4(x1[0], x1[1], x1[2], x1[3]);
        *(float4*)&lds[2][r][col] = make_float4(x2[0], x2[1], x2[2], x2[3]);
      }
    }
  }

  __syncthreads();

  // ---- Phase C: wave = (row, seg); lane handles img cols j0, j0+1 ----
  const int row = wv & 1;          // own row within tile
  const int seg = wv >> 1;         // 0..3: 128-col segment
  const int lc = 128 * seg + 2 * lane + 4;  // lds col of own first px

  float acc = 0.0f;
  float O[6][4];
#pragma unroll
  for (int p6 = 0; p6 < 6; ++p6) {
    *(float2*)&O[p6][0] = *(const float2*)&lds[p6][row][lc];
    *(float2*)&O[p6][2] = *(const float2*)&lds[p6][row][lc + 2];
  }

  __builtin_amdgcn_s_setprio(1);
  acc += contrib0<1>(O);
  acc += contrib0<2>(O);
  __builtin_amdgcn_s_setprio(0);

  {
    float N[6][6];
#pragma unroll
    for (int p6 = 0; p6 < 6; ++p6) {
      *(float2*)&N[p6][0] = *(const float2*)&lds[p6][row + 1][lc - 2];
      *(float2*)&N[p6][2] = *(const float2*)&lds[p6][row + 1][lc];
      *(float2*)&N[p6][4] = *(const float2*)&lds[p6][row + 1][lc + 2];
    }
    __builtin_amdgcn_s_setprio(1);
    acc += contribN<1, -2>(O, N);
    acc += contribN<1, -1>(O, N);
    acc += contribN<1, 0>(O, N);
    acc += contribN<1, 1>(O, N);
    acc += contribN<1, 2>(O, N);
    __builtin_amdgcn_s_setprio(0);
  }
  {
    float N[6][6];
#pragma unroll
    for (int p6 = 0; p6 < 6; ++p6) {
      *(float2*)&N[p6][0] = *(const float2*)&lds[p6][row + 2][lc - 2];
      *(float2*)&N[p6][2] = *(const float2*)&lds[p6][row + 2][lc];
      *(float2*)&N[p6][4] = *(const float2*)&lds[p6][row + 2][lc + 2];
    }
    __builtin_amdgcn_s_setprio(1);
    acc += contribN<2, -2>(O, N);
    acc += contribN<2, -1>(O, N);
    acc += contribN<2, 0>(O, N);
    acc += contribN<2, 1>(O, N);
    acc += contribN<2, 2>(O, N);
    __builtin_amdgcn_s_setprio(0);
  }

  // ---- reduction ----
#pragma unroll
  for (int o = 32; o > 0; o >>= 1) acc += __shfl_down(acc, o, 64);
  if (lane == 0) wsum[wv] = acc;
  __syncthreads();
  if (tid == 0) {
    float s = 0.0f;
#pragma unroll
    for (int wq = 0; wq < 8; ++wq) s += wsum[wq];
    atomicAdd(result, s);
  }
}

extern "C" void kernel_launch(void* const* d_in, const int* in_sizes, int n_in,
                              void* d_out, int out_size, void* d_ws, size_t ws_size,
                              hipStream_t stream) {
  const float* in = (const float*)d_in[0];
  const float* outp = (const float*)d_in[1];
  float* res = (float*)d_out;

  zero_out_kernel<<<1, 1, 0, stream>>>(res);

  dim3 grid(H_ / TH, B_, 1);  // (256, 16) = 4096 blocks
  smooth_loss_kernel<<<grid, NTHREADS, 0, stream>>>(in, outp, res);
}